// Round 3
// baseline (922.047 us; speedup 1.0000x reference)
//
#include <hip/hip_runtime.h>
#include <math.h>

#define CNW 9216000      // C*N*W = 96*1000*96
#define TOT 18432000     // B*C*N*W
#define EPSV 1e-5f
#define ITEMP 0.10206207261596575f   // 1/sqrt(96)

// ---------------- conv1x1: out[b,o,n,w] = sum_c W[o,c]*x[b,c,n,w] (+bias) ----
// one block per (b,n); LDS tiles padded to 100 floats/row (16B-aligned rows)
__global__ __launch_bounds__(256) void conv_k(const float* __restrict__ x,
    const float* __restrict__ w, const float* __restrict__ bias,
    float* __restrict__ out) {
  __shared__ float xt[96 * 100];
  __shared__ float wt[96 * 100];
  int b = blockIdx.x / 1000, n = blockIdx.x % 1000;
  int t = threadIdx.x;
  const float* xp = x + b * CNW + n * 96;
  for (int i = t; i < 9216; i += 256) {
    int cc = i / 96, j = i % 96;
    xt[cc * 100 + j] = xp[cc * 96000 + j];
    wt[cc * 100 + j] = w[i];            // wt[o][c] since i = o*96+c
  }
  __syncthreads();
  if (t < 192) {
    int wq = t % 24, og = t / 24;       // w = 4*wq+r, o = og*12+oo
    float4 acc[12];
#pragma unroll
    for (int oo = 0; oo < 12; ++oo) acc[oo] = make_float4(0.f, 0.f, 0.f, 0.f);
    for (int cq = 0; cq < 24; ++cq) {
      float4 xv0 = *(const float4*)&xt[(4 * cq + 0) * 100 + 4 * wq];
      float4 xv1 = *(const float4*)&xt[(4 * cq + 1) * 100 + 4 * wq];
      float4 xv2 = *(const float4*)&xt[(4 * cq + 2) * 100 + 4 * wq];
      float4 xv3 = *(const float4*)&xt[(4 * cq + 3) * 100 + 4 * wq];
#pragma unroll
      for (int oo = 0; oo < 12; ++oo) {
        int o = og * 12 + oo;
        float4 wv = *(const float4*)&wt[o * 100 + 4 * cq];
        acc[oo].x += wv.x * xv0.x + wv.y * xv1.x + wv.z * xv2.x + wv.w * xv3.x;
        acc[oo].y += wv.x * xv0.y + wv.y * xv1.y + wv.z * xv2.y + wv.w * xv3.y;
        acc[oo].z += wv.x * xv0.z + wv.y * xv1.z + wv.z * xv2.z + wv.w * xv3.z;
        acc[oo].w += wv.x * xv0.w + wv.y * xv1.w + wv.z * xv2.w + wv.w * xv3.w;
      }
    }
    float* op = out + b * CNW + n * 96 + 4 * wq;
#pragma unroll
    for (int oo = 0; oo < 12; ++oo) {
      int o = og * 12 + oo;
      float4 v = acc[oo];
      if (bias) { float bb = bias[o]; v.x += bb; v.y += bb; v.z += bb; v.w += bb; }
      *(float4*)&op[o * 96000] = v;
    }
  }
}

// ---------------- attention kernel A: block means -> sinkhorn -> top3 cut -> P
__global__ __launch_bounds__(256) void attnA_k(const float* __restrict__ feat,
                                               float* __restrict__ Pg) {
  int head = blockIdx.x;
  int b = head / 576, rem = head % 576, c = rem / 6, gr = rem % 6;
  const float* fb = feat + b * CNW + c * 96000 + gr * 16;
  __shared__ float qm[160];     // [10][16]
  __shared__ float L[110];      // [10][11]
  int t = threadIdx.x;
  if (t < 160) {
    int m = t / 16, j = t % 16;
    float s = 0.f;
    for (int ss = 0; ss < 100; ++ss) s += fb[(m * 100 + ss) * 96 + j];
    qm[m * 16 + j] = s * 0.01f;
  }
  __syncthreads();
  if (t < 100) {
    int m = t / 10, n2 = t % 10;
    float acc = 0.f;
#pragma unroll
    for (int j = 0; j < 16; ++j) acc += qm[m * 16 + j] * qm[n2 * 16 + j];
    L[m * 11 + n2] = acc * ITEMP;
  }
  __syncthreads();
  for (int it = 0; it < 8; ++it) {
    if (t < 10) {   // row LSE (axis=-1)
      float mx = -3.4e38f;
      for (int n2 = 0; n2 < 10; ++n2) mx = fmaxf(mx, L[t * 11 + n2]);
      float s = 0.f;
      for (int n2 = 0; n2 < 10; ++n2) s += expf(L[t * 11 + n2] - mx);
      float lse = mx + logf(s);
      for (int n2 = 0; n2 < 10; ++n2) L[t * 11 + n2] -= lse;
    }
    __syncthreads();
    if (t < 10) {   // col LSE (axis=-2)
      float mx = -3.4e38f;
      for (int m = 0; m < 10; ++m) mx = fmaxf(mx, L[m * 11 + t]);
      float s = 0.f;
      for (int m = 0; m < 10; ++m) s += expf(L[m * 11 + t] - mx);
      float lse = mx + logf(s);
      for (int m = 0; m < 10; ++m) L[m * 11 + t] -= lse;
    }
    __syncthreads();
  }
  if (t < 10) {
    float p[10];
#pragma unroll
    for (int n2 = 0; n2 < 10; ++n2) p[n2] = expf(L[t * 11 + n2]);
    int i1 = -1, i2 = -1;
    float m1 = -1.f, m2 = -1.f, m3 = -1.f;
#pragma unroll
    for (int n2 = 0; n2 < 10; ++n2) if (p[n2] > m1) { m1 = p[n2]; i1 = n2; }
#pragma unroll
    for (int n2 = 0; n2 < 10; ++n2) if (n2 != i1 && p[n2] > m2) { m2 = p[n2]; i2 = n2; }
#pragma unroll
    for (int n2 = 0; n2 < 10; ++n2) if (n2 != i1 && n2 != i2 && p[n2] > m3) m3 = p[n2];
#pragma unroll
    for (int n2 = 0; n2 < 10; ++n2)
      Pg[head * 100 + t * 10 + n2] = (p[n2] >= m3) ? p[n2] : 0.f;
  }
}

// ---------------- attention kernel B: per (head, m): mix, scores, softmax, PV
__global__ __launch_bounds__(256) void attnB_k(const float* __restrict__ feat,
    const float* __restrict__ Pg, float* __restrict__ out) {
  int m = blockIdx.x % 10;
  int head = blockIdx.x / 10;
  int b = head / 576, rem = head % 576, c = rem / 6, gr = rem % 6;
  const float* fb = feat + b * CNW + c * 96000 + gr * 16;
  __shared__ float qb[100 * 20];
  __shared__ float sk[100 * 20];
  __shared__ float sv[100 * 20];
  __shared__ float sc[100 * 104];   // transposed: sc[tt][s]
  __shared__ float rinv[100];
  int t = threadIdx.x;
  float p[10];
#pragma unroll
  for (int n2 = 0; n2 < 10; ++n2) p[n2] = Pg[head * 100 + m * 10 + n2];
  // load q-block; build mixed sk/sv (v = elu(k)) in registers, single LDS write
  for (int i4 = t; i4 < 400; i4 += 256) {
    int s = i4 >> 2, q = i4 & 3;
    float4 qv = *(const float4*)&fb[(m * 100 + s) * 96 + 4 * q];
    float4 ak = make_float4(0.f, 0.f, 0.f, 0.f);
    float4 av = make_float4(0.f, 0.f, 0.f, 0.f);
#pragma unroll
    for (int n2 = 0; n2 < 10; ++n2) {
      if (p[n2] != 0.f) {
        float4 kv = *(const float4*)&fb[(n2 * 100 + s) * 96 + 4 * q];
        float pe = p[n2];
        ak.x += pe * kv.x; ak.y += pe * kv.y; ak.z += pe * kv.z; ak.w += pe * kv.w;
        float ex = kv.x > 0.f ? kv.x : expm1f(kv.x);
        float ey = kv.y > 0.f ? kv.y : expm1f(kv.y);
        float ez = kv.z > 0.f ? kv.z : expm1f(kv.z);
        float ew = kv.w > 0.f ? kv.w : expm1f(kv.w);
        av.x += pe * ex; av.y += pe * ey; av.z += pe * ez; av.w += pe * ew;
      }
    }
    *(float4*)&qb[s * 20 + 4 * q] = qv;
    *(float4*)&sk[s * 20 + 4 * q] = ak;
    *(float4*)&sv[s * 20 + 4 * q] = av;
  }
  __syncthreads();
  // scores: thread owns 4 q-rows (hoisted to regs) x 10 tt columns
  if (t < 250) {
    int s4 = t / 10, tsub = t % 10;
    float4 q4[4][4];
#pragma unroll
    for (int r = 0; r < 4; ++r)
#pragma unroll
      for (int qq = 0; qq < 4; ++qq)
        q4[r][qq] = *(const float4*)&qb[(s4 * 4 + r) * 20 + 4 * qq];
    for (int k = 0; k < 10; ++k) {
      int tt = tsub + 10 * k;
      float4 k0 = *(const float4*)&sk[tt * 20 + 0];
      float4 k1 = *(const float4*)&sk[tt * 20 + 4];
      float4 k2 = *(const float4*)&sk[tt * 20 + 8];
      float4 k3 = *(const float4*)&sk[tt * 20 + 12];
#pragma unroll
      for (int r = 0; r < 4; ++r) {
        float d0 = q4[r][0].x * k0.x + q4[r][0].y * k0.y + q4[r][0].z * k0.z + q4[r][0].w * k0.w;
        float d1 = q4[r][1].x * k1.x + q4[r][1].y * k1.y + q4[r][1].z * k1.z + q4[r][1].w * k1.w;
        float d2 = q4[r][2].x * k2.x + q4[r][2].y * k2.y + q4[r][2].z * k2.z + q4[r][2].w * k2.w;
        float d3 = q4[r][3].x * k3.x + q4[r][3].y * k3.y + q4[r][3].z * k3.z + q4[r][3].w * k3.w;
        sc[tt * 104 + s4 * 4 + r] = (d0 + d1 + d2 + d3) * ITEMP;
      }
    }
  }
  __syncthreads();
  // softmax over tt per q-row s = t (column of transposed sc)
  if (t < 100) {
    float mx = -3.4e38f;
    for (int tt = 0; tt < 100; ++tt) mx = fmaxf(mx, sc[tt * 104 + t]);
    float sum = 0.f;
    for (int tt = 0; tt < 100; ++tt) {
      float e = expf(sc[tt * 104 + t] - mx);
      sc[tt * 104 + t] = e;
      sum += e;
    }
    rinv[t] = 1.f / sum;
  }
  __syncthreads();
  // o = a @ sv : thread owns (4 s-rows) x (4 j-cols)
  if (t < 100) {
    int sq = t >> 2, jq = t & 3;
    float4 acc0 = make_float4(0.f, 0.f, 0.f, 0.f);
    float4 acc1 = acc0, acc2 = acc0, acc3 = acc0;
    for (int tt = 0; tt < 100; ++tt) {
      float4 a4 = *(const float4*)&sc[tt * 104 + sq * 4];
      float4 vv = *(const float4*)&sv[tt * 20 + 4 * jq];
      acc0.x += a4.x * vv.x; acc0.y += a4.x * vv.y; acc0.z += a4.x * vv.z; acc0.w += a4.x * vv.w;
      acc1.x += a4.y * vv.x; acc1.y += a4.y * vv.y; acc1.z += a4.y * vv.z; acc1.w += a4.y * vv.w;
      acc2.x += a4.z * vv.x; acc2.y += a4.z * vv.y; acc2.z += a4.z * vv.z; acc2.w += a4.z * vv.w;
      acc3.x += a4.w * vv.x; acc3.y += a4.w * vv.y; acc3.z += a4.w * vv.z; acc3.w += a4.w * vv.w;
    }
    float* ob = out + b * CNW + c * 96000 + gr * 16;
    float4 accs[4] = {acc0, acc1, acc2, acc3};
#pragma unroll
    for (int r = 0; r < 4; ++r) {
      int s = sq * 4 + r;
      float ri = rinv[s];
      float4 v = make_float4(accs[r].x * ri, accs[r].y * ri, accs[r].z * ri, accs[r].w * ri);
      *(float4*)&ob[(m * 100 + s) * 96 + 4 * jq] = v;
    }
  }
}

// ---------------- t = swapaxes(feat_attn,1,3) + x  (per (b,n) 96x96 tile) ----
__global__ __launch_bounds__(256) void trans_add_k(const float* __restrict__ z,
    const float* __restrict__ x, float* __restrict__ out) {
  __shared__ float ld[96 * 97];
  int b = blockIdx.x / 1000, n = blockIdx.x % 1000;
  int t = threadIdx.x;
  const float* zp = z + b * CNW + n * 96;
  for (int i = t; i < 9216; i += 256) {
    int r = i / 96, col = i % 96;
    ld[r * 97 + col] = zp[r * 96000 + col];
  }
  __syncthreads();
  const float* xp = x + b * CNW + n * 96;
  float* op = out + b * CNW + n * 96;
  for (int i = t; i < 9216; i += 256) {
    int cc = i / 96, ww = i % 96;
    op[cc * 96000 + ww] = ld[ww * 97 + cc] + xp[cc * 96000 + ww];
  }
}

// ---------------- GN stats: 12 contiguous (b,group) slices of 1.536M floats --
__global__ __launch_bounds__(256) void gnstats_k(const float* __restrict__ a,
                                                 float* __restrict__ st) {
  int slice = blockIdx.x >> 5, chunk = blockIdx.x & 31;
  const float4* p = (const float4*)(a + slice * 1536000 + chunk * 48000);
  float s = 0.f, q = 0.f;
  for (int i = threadIdx.x; i < 12000; i += 256) {
    float4 v = p[i];
    s += v.x + v.y + v.z + v.w;
    q += v.x * v.x + v.y * v.y + v.z * v.z + v.w * v.w;
  }
#pragma unroll
  for (int d = 32; d >= 1; d >>= 1) { s += __shfl_down(s, d, 64); q += __shfl_down(q, d, 64); }
  __shared__ float ls[4], lq[4];
  int wid = threadIdx.x >> 6;
  if ((threadIdx.x & 63) == 0) { ls[wid] = s; lq[wid] = q; }
  __syncthreads();
  if (threadIdx.x == 0) {
    atomicAdd(&st[slice * 2 + 0], ls[0] + ls[1] + ls[2] + ls[3]);
    atomicAdd(&st[slice * 2 + 1], lq[0] + lq[1] + lq[2] + lq[3]);
  }
}

// ---------------- per-channel / per-(b,channel) stats over one channel slice -
template <int PER_CH>
__global__ __launch_bounds__(256) void chstats_k(const float* __restrict__ src,
                                                 float* __restrict__ st) {
  int b = blockIdx.x / 96, o = blockIdx.x % 96;
  const float4* p = (const float4*)(src + b * CNW + o * 96000);
  float s = 0.f, q = 0.f;
  for (int i = threadIdx.x; i < 24000; i += 256) {
    float4 v = p[i];
    s += v.x + v.y + v.z + v.w;
    q += v.x * v.x + v.y * v.y + v.z * v.z + v.w * v.w;
  }
#pragma unroll
  for (int d = 32; d >= 1; d >>= 1) { s += __shfl_down(s, d, 64); q += __shfl_down(q, d, 64); }
  __shared__ float ls[4], lq[4];
  int wid = threadIdx.x >> 6;
  if ((threadIdx.x & 63) == 0) { ls[wid] = s; lq[wid] = q; }
  __syncthreads();
  if (threadIdx.x == 0) {
    float S = ls[0] + ls[1] + ls[2] + ls[3];
    float Q = lq[0] + lq[1] + lq[2] + lq[3];
    if (PER_CH) { atomicAdd(&st[o * 2 + 0], S); atomicAdd(&st[o * 2 + 1], Q); }
    else { st[(b * 96 + o) * 2 + 0] = S; st[(b * 96 + o) * 2 + 1] = Q; }
  }
}

// ---------------- GroupNorm apply (in place) --------------------------------
__global__ __launch_bounds__(256) void gn2_k(float* __restrict__ a,
    const float* __restrict__ st, const float* __restrict__ gw,
    const float* __restrict__ gb) {
  int stride = gridDim.x * 256;
  for (int i4 = blockIdx.x * 256 + threadIdx.x; i4 < 4608000; i4 += stride) {
    int i = i4 * 4;
    int b = i / CNW, c = (i / 96000) % 96, g = c >> 4;
    float m = st[(b * 6 + g) * 2 + 0] * (1.f / 1536000.f);
    float v = st[(b * 6 + g) * 2 + 1] * (1.f / 1536000.f) - m * m;
    float scv = rsqrtf(v + EPSV) * gw[c];
    float sh = gb[c] - m * scv;
    float4 x = ((float4*)a)[i4];
    x.x = x.x * scv + sh; x.y = x.y * scv + sh; x.z = x.z * scv + sh; x.w = x.w * scv + sh;
    ((float4*)a)[i4] = x;
  }
}

// ---------------- left1 = relu(BN1(IN(l1))) in place -------------------------
// BN-after-IN analytics: mean = 0 exactly; var[c] = avg_b v_bc/(v_bc+eps)
__global__ __launch_bounds__(256) void bnin_relu_k(float* __restrict__ tbuf,
    const float* __restrict__ st, const float* __restrict__ bw,
    const float* __restrict__ bb) {
  int stride = gridDim.x * 256;
  for (int i4 = blockIdx.x * 256 + threadIdx.x; i4 < 4608000; i4 += stride) {
    int i = i4 * 4;
    int b = i / CNW, o = (i / 96000) % 96;
    const float inv = 1.f / 96000.f;
    float m0 = st[o * 2] * inv,        v0 = st[o * 2 + 1] * inv - m0 * m0;
    float m1 = st[(96 + o) * 2] * inv, v1 = st[(96 + o) * 2 + 1] * inv - m1 * m1;
    float bv = 0.5f * (v0 / (v0 + EPSV) + v1 / (v1 + EPSV));
    float bscale = rsqrtf(bv + EPSV) * bw[o];
    float mi = b ? m1 : m0, vi = b ? v1 : v0;
    float scv = rsqrtf(vi + EPSV) * bscale;
    float sh = bb[o] - mi * scv;
    float4 x = ((float4*)tbuf)[i4];
    x.x = fmaxf(x.x * scv + sh, 0.f); x.y = fmaxf(x.y * scv + sh, 0.f);
    x.z = fmaxf(x.z * scv + sh, 0.f); x.w = fmaxf(x.w * scv + sh, 0.f);
    ((float4*)tbuf)[i4] = x;
  }
}

// ---------------- out = relu( BN2(IN(l2)) + BNr(t1) ), in place over d_out ---
__global__ __launch_bounds__(256) void final_k(float* __restrict__ outp,
    const float* __restrict__ l2, const float* __restrict__ stR,
    const float* __restrict__ st2, const float* __restrict__ rw,
    const float* __restrict__ rb, const float* __restrict__ w2,
    const float* __restrict__ b2) {
  int stride = gridDim.x * 256;
  for (int i4 = blockIdx.x * 256 + threadIdx.x; i4 < 4608000; i4 += stride) {
    int i = i4 * 4;
    int b = i / CNW, o = (i / 96000) % 96;
    // right path: plain BN of raw conv output held in outp
    float mr = stR[o * 2] * (1.f / 192000.f);
    float vr = stR[o * 2 + 1] * (1.f / 192000.f) - mr * mr;
    float rs = rsqrtf(vr + EPSV) * rw[o];
    float rsh = rb[o] - mr * rs;
    // left path: IN then analytic BN
    const float inv = 1.f / 96000.f;
    float m0 = st2[o * 2] * inv,        v0 = st2[o * 2 + 1] * inv - m0 * m0;
    float m1 = st2[(96 + o) * 2] * inv, v1 = st2[(96 + o) * 2 + 1] * inv - m1 * m1;
    float bv = 0.5f * (v0 / (v0 + EPSV) + v1 / (v1 + EPSV));
    float ls = rsqrtf(bv + EPSV) * w2[o];
    float mi = b ? m1 : m0, vi = b ? v1 : v0;
    float lsc = rsqrtf(vi + EPSV) * ls;
    float lsh = b2[o] - mi * lsc;
    float4 R = ((float4*)outp)[i4];
    float4 L = ((const float4*)l2)[i4];
    float4 O;
    O.x = fmaxf(R.x * rs + rsh + L.x * lsc + lsh, 0.f);
    O.y = fmaxf(R.y * rs + rsh + L.y * lsc + lsh, 0.f);
    O.z = fmaxf(R.z * rs + rsh + L.z * lsc + lsh, 0.f);
    O.w = fmaxf(R.w * rs + rsh + L.w * lsc + lsh, 0.f);
    ((float4*)outp)[i4] = O;
  }
}

extern "C" void kernel_launch(void* const* d_in, const int* in_sizes, int n_in,
                              void* d_out, int out_size, void* d_ws, size_t ws_size,
                              hipStream_t stream) {
  const float* x        = (const float*)d_in[0];
  const float* w_linear = (const float*)d_in[1];
  const float* gn_w     = (const float*)d_in[2];
  const float* gn_b     = (const float*)d_in[3];
  const float* w_right  = (const float*)d_in[4];
  const float* b_right  = (const float*)d_in[5];
  const float* bn_r_w   = (const float*)d_in[6];
  const float* bn_r_b   = (const float*)d_in[7];
  const float* w_l1     = (const float*)d_in[8];
  const float* b_l1     = (const float*)d_in[9];
  const float* bn1_w    = (const float*)d_in[10];
  const float* bn1_b    = (const float*)d_in[11];
  const float* w_l2     = (const float*)d_in[12];
  const float* b_l2     = (const float*)d_in[13];
  const float* bn2_w    = (const float*)d_in[14];
  const float* bn2_b    = (const float*)d_in[15];
  float* out = (float*)d_out;

  float* A     = (float*)d_ws;          // 18,432,000 floats
  float* Bb    = A + TOT;               // 18,432,000 floats
  float* Pg    = Bb + TOT;              // 115,200 floats
  float* stGN  = Pg + 115200;           // 24
  float* stBNr = stGN + 24;             // 192
  float* stIN1 = stBNr + 192;           // 384
  float* stIN2 = stIN1 + 384;           // 384

  hipMemsetAsync(stGN, 0, 984 * sizeof(float), stream);

  // feat = conv1x1(x, w_linear)  -> A
  conv_k<<<2000, 256, 0, stream>>>(x, w_linear, nullptr, A);
  // block means + sinkhorn + top-3 cut -> P
  attnA_k<<<1152, 256, 0, stream>>>(A, Pg);
  // attention -> Bb (stored directly in feat_attn [B,C,N,W] layout)
  attnB_k<<<11520, 256, 0, stream>>>(A, Pg, Bb);
  // t = swapaxes(feat_attn,1,3) + x -> A
  trans_add_k<<<2000, 256, 0, stream>>>(Bb, x, A);
  // groupnorm stats + apply (y in A)
  gnstats_k<<<384, 256, 0, stream>>>(A, stGN);
  gn2_k<<<2048, 256, 0, stream>>>(A, stGN, gn_w, gn_b);
  // right = conv(y, w_right)+b -> d_out (raw); BN stats
  conv_k<<<2000, 256, 0, stream>>>(A, w_right, b_right, out);
  chstats_k<1><<<192, 256, 0, stream>>>(out, stBNr);
  // l1 = conv(y, w_l1)+b -> Bb (raw); IN stats; left1 = relu(BN1(IN(l1))) in place
  conv_k<<<2000, 256, 0, stream>>>(A, w_l1, b_l1, Bb);
  chstats_k<0><<<192, 256, 0, stream>>>(Bb, stIN1);
  bnin_relu_k<<<2048, 256, 0, stream>>>(Bb, stIN1, bn1_w, bn1_b);
  // l2 = conv(left1, w_l2)+b -> A (raw); IN stats
  conv_k<<<2000, 256, 0, stream>>>(Bb, w_l2, b_l2, A);
  chstats_k<0><<<192, 256, 0, stream>>>(A, stIN2);
  // out = relu(BN2(IN(l2)) + BNr(right_raw))
  final_k<<<2048, 256, 0, stream>>>(out, A, stBNr, stIN2,
                                    bn_r_w, bn_r_b, bn2_w, bn2_b);
}

// Round 4
// 920.118 us; speedup vs baseline: 1.0021x; 1.0021x over previous
//
#include <hip/hip_runtime.h>
#include <math.h>

#define CNW 9216000      // C*N*W = 96*1000*96
#define TOT 18432000     // B*C*N*W
#define EPSV 1e-5f
#define ITEMP 0.10206207261596575f   // 1/sqrt(96)

// ---------------- conv1x1: out[b,o,n,w] = sum_c W[o,c]*x[b,c,n,w] (+bias) ----
// one block per (b,n); LDS tiles padded to 100 floats/row (16B-aligned rows)
__global__ __launch_bounds__(256) void conv_k(const float* __restrict__ x,
    const float* __restrict__ w, const float* __restrict__ bias,
    float* __restrict__ out) {
  __shared__ float xt[96 * 100];
  __shared__ float wt[96 * 100];
  int b = blockIdx.x / 1000, n = blockIdx.x % 1000;
  int t = threadIdx.x;
  const float* xp = x + b * CNW + n * 96;
  for (int i = t; i < 9216; i += 256) {
    int cc = i / 96, j = i % 96;
    xt[cc * 100 + j] = xp[cc * 96000 + j];
    wt[cc * 100 + j] = w[i];            // wt[o][c] since i = o*96+c
  }
  __syncthreads();
  if (t < 192) {
    int wq = t % 24, og = t / 24;       // w = 4*wq+r, o = og*12+oo
    float4 acc[12];
#pragma unroll
    for (int oo = 0; oo < 12; ++oo) acc[oo] = make_float4(0.f, 0.f, 0.f, 0.f);
    for (int cq = 0; cq < 24; ++cq) {
      float4 xv0 = *(const float4*)&xt[(4 * cq + 0) * 100 + 4 * wq];
      float4 xv1 = *(const float4*)&xt[(4 * cq + 1) * 100 + 4 * wq];
      float4 xv2 = *(const float4*)&xt[(4 * cq + 2) * 100 + 4 * wq];
      float4 xv3 = *(const float4*)&xt[(4 * cq + 3) * 100 + 4 * wq];
#pragma unroll
      for (int oo = 0; oo < 12; ++oo) {
        int o = og * 12 + oo;
        float4 wv = *(const float4*)&wt[o * 100 + 4 * cq];
        acc[oo].x += wv.x * xv0.x + wv.y * xv1.x + wv.z * xv2.x + wv.w * xv3.x;
        acc[oo].y += wv.x * xv0.y + wv.y * xv1.y + wv.z * xv2.y + wv.w * xv3.y;
        acc[oo].z += wv.x * xv0.z + wv.y * xv1.z + wv.z * xv2.z + wv.w * xv3.z;
        acc[oo].w += wv.x * xv0.w + wv.y * xv1.w + wv.z * xv2.w + wv.w * xv3.w;
      }
    }
    float* op = out + b * CNW + n * 96 + 4 * wq;
#pragma unroll
    for (int oo = 0; oo < 12; ++oo) {
      int o = og * 12 + oo;
      float4 v = acc[oo];
      if (bias) { float bb = bias[o]; v.x += bb; v.y += bb; v.z += bb; v.w += bb; }
      *(float4*)&op[o * 96000] = v;
    }
  }
}

// ---------------- attention kernel A: block means -> sinkhorn -> top3 cut -> P
__global__ __launch_bounds__(256) void attnA_k(const float* __restrict__ feat,
                                               float* __restrict__ Pg) {
  int head = blockIdx.x;
  int b = head / 576, rem = head % 576, c = rem / 6, gr = rem % 6;
  const float* fb = feat + b * CNW + c * 96000 + gr * 16;
  __shared__ float qm[160];     // [10][16]
  __shared__ float L[110];      // [10][11]
  int t = threadIdx.x;
  if (t < 160) {
    int m = t / 16, j = t % 16;
    float s = 0.f;
    for (int ss = 0; ss < 100; ++ss) s += fb[(m * 100 + ss) * 96 + j];
    qm[m * 16 + j] = s * 0.01f;
  }
  __syncthreads();
  if (t < 100) {
    int m = t / 10, n2 = t % 10;
    float acc = 0.f;
#pragma unroll
    for (int j = 0; j < 16; ++j) acc += qm[m * 16 + j] * qm[n2 * 16 + j];
    L[m * 11 + n2] = acc * ITEMP;
  }
  __syncthreads();
  for (int it = 0; it < 8; ++it) {
    if (t < 10) {   // row LSE (axis=-1)
      float mx = -3.4e38f;
      for (int n2 = 0; n2 < 10; ++n2) mx = fmaxf(mx, L[t * 11 + n2]);
      float s = 0.f;
      for (int n2 = 0; n2 < 10; ++n2) s += expf(L[t * 11 + n2] - mx);
      float lse = mx + logf(s);
      for (int n2 = 0; n2 < 10; ++n2) L[t * 11 + n2] -= lse;
    }
    __syncthreads();
    if (t < 10) {   // col LSE (axis=-2)
      float mx = -3.4e38f;
      for (int m = 0; m < 10; ++m) mx = fmaxf(mx, L[m * 11 + t]);
      float s = 0.f;
      for (int m = 0; m < 10; ++m) s += expf(L[m * 11 + t] - mx);
      float lse = mx + logf(s);
      for (int m = 0; m < 10; ++m) L[m * 11 + t] -= lse;
    }
    __syncthreads();
  }
  if (t < 10) {
    float p[10];
#pragma unroll
    for (int n2 = 0; n2 < 10; ++n2) p[n2] = expf(L[t * 11 + n2]);
    int i1 = -1, i2 = -1;
    float m1 = -1.f, m2 = -1.f, m3 = -1.f;
#pragma unroll
    for (int n2 = 0; n2 < 10; ++n2) if (p[n2] > m1) { m1 = p[n2]; i1 = n2; }
#pragma unroll
    for (int n2 = 0; n2 < 10; ++n2) if (n2 != i1 && p[n2] > m2) { m2 = p[n2]; i2 = n2; }
#pragma unroll
    for (int n2 = 0; n2 < 10; ++n2) if (n2 != i1 && n2 != i2 && p[n2] > m3) m3 = p[n2];
#pragma unroll
    for (int n2 = 0; n2 < 10; ++n2)
      Pg[head * 100 + t * 10 + n2] = (p[n2] >= m3) ? p[n2] : 0.f;
  }
}

// ---------------- attention kernel B: per (head, m): mix, scores, softmax, PV
__global__ __launch_bounds__(256) void attnB_k(const float* __restrict__ feat,
    const float* __restrict__ Pg, float* __restrict__ out) {
  int m = blockIdx.x % 10;
  int head = blockIdx.x / 10;
  int b = head / 576, rem = head % 576, c = rem / 6, gr = rem % 6;
  const float* fb = feat + b * CNW + c * 96000 + gr * 16;
  __shared__ float qb[100 * 20];
  __shared__ float sk[100 * 20];
  __shared__ float sv[100 * 20];
  __shared__ float sc[100 * 104];   // transposed: sc[tt][s]
  __shared__ float rinv[100];
  int t = threadIdx.x;
  float p[10];
#pragma unroll
  for (int n2 = 0; n2 < 10; ++n2) p[n2] = Pg[head * 100 + m * 10 + n2];
  // load q-block; build mixed sk/sv (v = elu(k)) in registers, single LDS write
  for (int i4 = t; i4 < 400; i4 += 256) {
    int s = i4 >> 2, q = i4 & 3;
    float4 qv = *(const float4*)&fb[(m * 100 + s) * 96 + 4 * q];
    float4 ak = make_float4(0.f, 0.f, 0.f, 0.f);
    float4 av = make_float4(0.f, 0.f, 0.f, 0.f);
#pragma unroll
    for (int n2 = 0; n2 < 10; ++n2) {
      if (p[n2] != 0.f) {
        float4 kv = *(const float4*)&fb[(n2 * 100 + s) * 96 + 4 * q];
        float pe = p[n2];
        ak.x += pe * kv.x; ak.y += pe * kv.y; ak.z += pe * kv.z; ak.w += pe * kv.w;
        float ex = kv.x > 0.f ? kv.x : expm1f(kv.x);
        float ey = kv.y > 0.f ? kv.y : expm1f(kv.y);
        float ez = kv.z > 0.f ? kv.z : expm1f(kv.z);
        float ew = kv.w > 0.f ? kv.w : expm1f(kv.w);
        av.x += pe * ex; av.y += pe * ey; av.z += pe * ez; av.w += pe * ew;
      }
    }
    *(float4*)&qb[s * 20 + 4 * q] = qv;
    *(float4*)&sk[s * 20 + 4 * q] = ak;
    *(float4*)&sv[s * 20 + 4 * q] = av;
  }
  __syncthreads();
  // scores: thread owns 4 q-rows (hoisted to regs) x 10 tt columns
  if (t < 250) {
    int s4 = t / 10, tsub = t % 10;
    float4 q4[4][4];
#pragma unroll
    for (int r = 0; r < 4; ++r)
#pragma unroll
      for (int qq = 0; qq < 4; ++qq)
        q4[r][qq] = *(const float4*)&qb[(s4 * 4 + r) * 20 + 4 * qq];
    for (int k = 0; k < 10; ++k) {
      int tt = tsub + 10 * k;
      float4 k0 = *(const float4*)&sk[tt * 20 + 0];
      float4 k1 = *(const float4*)&sk[tt * 20 + 4];
      float4 k2 = *(const float4*)&sk[tt * 20 + 8];
      float4 k3 = *(const float4*)&sk[tt * 20 + 12];
#pragma unroll
      for (int r = 0; r < 4; ++r) {
        float d0 = q4[r][0].x * k0.x + q4[r][0].y * k0.y + q4[r][0].z * k0.z + q4[r][0].w * k0.w;
        float d1 = q4[r][1].x * k1.x + q4[r][1].y * k1.y + q4[r][1].z * k1.z + q4[r][1].w * k1.w;
        float d2 = q4[r][2].x * k2.x + q4[r][2].y * k2.y + q4[r][2].z * k2.z + q4[r][2].w * k2.w;
        float d3 = q4[r][3].x * k3.x + q4[r][3].y * k3.y + q4[r][3].z * k3.z + q4[r][3].w * k3.w;
        sc[tt * 104 + s4 * 4 + r] = (d0 + d1 + d2 + d3) * ITEMP;
      }
    }
  }
  __syncthreads();
  // softmax over tt per q-row s = t (column of transposed sc)
  if (t < 100) {
    float mx = -3.4e38f;
    for (int tt = 0; tt < 100; ++tt) mx = fmaxf(mx, sc[tt * 104 + t]);
    float sum = 0.f;
    for (int tt = 0; tt < 100; ++tt) {
      float e = expf(sc[tt * 104 + t] - mx);
      sc[tt * 104 + t] = e;
      sum += e;
    }
    rinv[t] = 1.f / sum;
  }
  __syncthreads();
  // o = a @ sv : thread owns (4 s-rows) x (4 j-cols)
  if (t < 100) {
    int sq = t >> 2, jq = t & 3;
    float4 acc0 = make_float4(0.f, 0.f, 0.f, 0.f);
    float4 acc1 = acc0, acc2 = acc0, acc3 = acc0;
    for (int tt = 0; tt < 100; ++tt) {
      float4 a4 = *(const float4*)&sc[tt * 104 + sq * 4];
      float4 vv = *(const float4*)&sv[tt * 20 + 4 * jq];
      acc0.x += a4.x * vv.x; acc0.y += a4.x * vv.y; acc0.z += a4.x * vv.z; acc0.w += a4.x * vv.w;
      acc1.x += a4.y * vv.x; acc1.y += a4.y * vv.y; acc1.z += a4.y * vv.z; acc1.w += a4.y * vv.w;
      acc2.x += a4.z * vv.x; acc2.y += a4.z * vv.y; acc2.z += a4.z * vv.z; acc2.w += a4.z * vv.w;
      acc3.x += a4.w * vv.x; acc3.y += a4.w * vv.y; acc3.z += a4.w * vv.z; acc3.w += a4.w * vv.w;
    }
    float* ob = out + b * CNW + c * 96000 + gr * 16;
    float4 accs[4] = {acc0, acc1, acc2, acc3};
#pragma unroll
    for (int r = 0; r < 4; ++r) {
      int s = sq * 4 + r;
      float ri = rinv[s];
      float4 v = make_float4(accs[r].x * ri, accs[r].y * ri, accs[r].z * ri, accs[r].w * ri);
      *(float4*)&ob[(m * 100 + s) * 96 + 4 * jq] = v;
    }
  }
}

// ---------------- t = swapaxes(feat_attn,1,3) + x  (per (b,n) 96x96 tile) ----
__global__ __launch_bounds__(256) void trans_add_k(const float* __restrict__ z,
    const float* __restrict__ x, float* __restrict__ out) {
  __shared__ float ld[96 * 97];
  int b = blockIdx.x / 1000, n = blockIdx.x % 1000;
  int t = threadIdx.x;
  const float* zp = z + b * CNW + n * 96;
  for (int i = t; i < 9216; i += 256) {
    int r = i / 96, col = i % 96;
    ld[r * 97 + col] = zp[r * 96000 + col];
  }
  __syncthreads();
  const float* xp = x + b * CNW + n * 96;
  float* op = out + b * CNW + n * 96;
  for (int i = t; i < 9216; i += 256) {
    int cc = i / 96, ww = i % 96;
    op[cc * 96000 + ww] = ld[ww * 97 + cc] + xp[cc * 96000 + ww];
  }
}

// ---------------- GN stats: 12 contiguous (b,group) slices of 1.536M floats --
__global__ __launch_bounds__(256) void gnstats_k(const float* __restrict__ a,
                                                 float* __restrict__ st) {
  int slice = blockIdx.x >> 5, chunk = blockIdx.x & 31;
  const float4* p = (const float4*)(a + slice * 1536000 + chunk * 48000);
  float s = 0.f, q = 0.f;
  for (int i = threadIdx.x; i < 12000; i += 256) {
    float4 v = p[i];
    s += v.x + v.y + v.z + v.w;
    q += v.x * v.x + v.y * v.y + v.z * v.z + v.w * v.w;
  }
#pragma unroll
  for (int d = 32; d >= 1; d >>= 1) { s += __shfl_down(s, d, 64); q += __shfl_down(q, d, 64); }
  __shared__ float ls[4], lq[4];
  int wid = threadIdx.x >> 6;
  if ((threadIdx.x & 63) == 0) { ls[wid] = s; lq[wid] = q; }
  __syncthreads();
  if (threadIdx.x == 0) {
    atomicAdd(&st[slice * 2 + 0], ls[0] + ls[1] + ls[2] + ls[3]);
    atomicAdd(&st[slice * 2 + 1], lq[0] + lq[1] + lq[2] + lq[3]);
  }
}

// ---------------- per-channel / per-(b,channel) stats over one channel slice -
template <int PER_CH>
__global__ __launch_bounds__(256) void chstats_k(const float* __restrict__ src,
                                                 float* __restrict__ st) {
  int b = blockIdx.x / 96, o = blockIdx.x % 96;
  const float4* p = (const float4*)(src + b * CNW + o * 96000);
  float s = 0.f, q = 0.f;
  for (int i = threadIdx.x; i < 24000; i += 256) {
    float4 v = p[i];
    s += v.x + v.y + v.z + v.w;
    q += v.x * v.x + v.y * v.y + v.z * v.z + v.w * v.w;
  }
#pragma unroll
  for (int d = 32; d >= 1; d >>= 1) { s += __shfl_down(s, d, 64); q += __shfl_down(q, d, 64); }
  __shared__ float ls[4], lq[4];
  int wid = threadIdx.x >> 6;
  if ((threadIdx.x & 63) == 0) { ls[wid] = s; lq[wid] = q; }
  __syncthreads();
  if (threadIdx.x == 0) {
    float S = ls[0] + ls[1] + ls[2] + ls[3];
    float Q = lq[0] + lq[1] + lq[2] + lq[3];
    if (PER_CH) { atomicAdd(&st[o * 2 + 0], S); atomicAdd(&st[o * 2 + 1], Q); }
    else { st[(b * 96 + o) * 2 + 0] = S; st[(b * 96 + o) * 2 + 1] = Q; }
  }
}

// ---------------- GroupNorm apply (in place) --------------------------------
__global__ __launch_bounds__(256) void gn2_k(float* __restrict__ a,
    const float* __restrict__ st, const float* __restrict__ gw,
    const float* __restrict__ gb) {
  int stride = gridDim.x * 256;
  for (int i4 = blockIdx.x * 256 + threadIdx.x; i4 < 4608000; i4 += stride) {
    int i = i4 * 4;
    int b = i / CNW, c = (i / 96000) % 96, g = c >> 4;
    float m = st[(b * 6 + g) * 2 + 0] * (1.f / 1536000.f);
    float v = st[(b * 6 + g) * 2 + 1] * (1.f / 1536000.f) - m * m;
    float scv = rsqrtf(v + EPSV) * gw[c];
    float sh = gb[c] - m * scv;
    float4 x = ((float4*)a)[i4];
    x.x = x.x * scv + sh; x.y = x.y * scv + sh; x.z = x.z * scv + sh; x.w = x.w * scv + sh;
    ((float4*)a)[i4] = x;
  }
}

// ---------------- left1 = relu(BN1(IN(l1))) in place -------------------------
// BN-after-IN analytics: mean = 0 exactly; var[c] = avg_b v_bc/(v_bc+eps)
__global__ __launch_bounds__(256) void bnin_relu_k(float* __restrict__ tbuf,
    const float* __restrict__ st, const float* __restrict__ bw,
    const float* __restrict__ bb) {
  int stride = gridDim.x * 256;
  for (int i4 = blockIdx.x * 256 + threadIdx.x; i4 < 4608000; i4 += stride) {
    int i = i4 * 4;
    int b = i / CNW, o = (i / 96000) % 96;
    const float inv = 1.f / 96000.f;
    float m0 = st[o * 2] * inv,        v0 = st[o * 2 + 1] * inv - m0 * m0;
    float m1 = st[(96 + o) * 2] * inv, v1 = st[(96 + o) * 2 + 1] * inv - m1 * m1;
    float bv = 0.5f * (v0 / (v0 + EPSV) + v1 / (v1 + EPSV));
    float bscale = rsqrtf(bv + EPSV) * bw[o];
    float mi = b ? m1 : m0, vi = b ? v1 : v0;
    float scv = rsqrtf(vi + EPSV) * bscale;
    float sh = bb[o] - mi * scv;
    float4 x = ((float4*)tbuf)[i4];
    x.x = fmaxf(x.x * scv + sh, 0.f); x.y = fmaxf(x.y * scv + sh, 0.f);
    x.z = fmaxf(x.z * scv + sh, 0.f); x.w = fmaxf(x.w * scv + sh, 0.f);
    ((float4*)tbuf)[i4] = x;
  }
}

// ---------------- out = relu( BN2(IN(l2)) + BNr(t1) ), in place over d_out ---
__global__ __launch_bounds__(256) void final_k(float* __restrict__ outp,
    const float* __restrict__ l2, const float* __restrict__ stR,
    const float* __restrict__ st2, const float* __restrict__ rw,
    const float* __restrict__ rb, const float* __restrict__ w2,
    const float* __restrict__ b2) {
  int stride = gridDim.x * 256;
  for (int i4 = blockIdx.x * 256 + threadIdx.x; i4 < 4608000; i4 += stride) {
    int i = i4 * 4;
    int b = i / CNW, o = (i / 96000) % 96;
    // right path: plain BN of raw conv output held in outp
    float mr = stR[o * 2] * (1.f / 192000.f);
    float vr = stR[o * 2 + 1] * (1.f / 192000.f) - mr * mr;
    float rs = rsqrtf(vr + EPSV) * rw[o];
    float rsh = rb[o] - mr * rs;
    // left path: IN then analytic BN
    const float inv = 1.f / 96000.f;
    float m0 = st2[o * 2] * inv,        v0 = st2[o * 2 + 1] * inv - m0 * m0;
    float m1 = st2[(96 + o) * 2] * inv, v1 = st2[(96 + o) * 2 + 1] * inv - m1 * m1;
    float bv = 0.5f * (v0 / (v0 + EPSV) + v1 / (v1 + EPSV));
    float ls = rsqrtf(bv + EPSV) * w2[o];
    float mi = b ? m1 : m0, vi = b ? v1 : v0;
    float lsc = rsqrtf(vi + EPSV) * ls;
    float lsh = b2[o] - mi * lsc;
    float4 R = ((float4*)outp)[i4];
    float4 L = ((const float4*)l2)[i4];
    float4 O;
    O.x = fmaxf(R.x * rs + rsh + L.x * lsc + lsh, 0.f);
    O.y = fmaxf(R.y * rs + rsh + L.y * lsc + lsh, 0.f);
    O.z = fmaxf(R.z * rs + rsh + L.z * lsc + lsh, 0.f);
    O.w = fmaxf(R.w * rs + rsh + L.w * lsc + lsh, 0.f);
    ((float4*)outp)[i4] = O;
  }
}

extern "C" void kernel_launch(void* const* d_in, const int* in_sizes, int n_in,
                              void* d_out, int out_size, void* d_ws, size_t ws_size,
                              hipStream_t stream) {
  const float* x        = (const float*)d_in[0];
  const float* w_linear = (const float*)d_in[1];
  const float* gn_w     = (const float*)d_in[2];
  const float* gn_b     = (const float*)d_in[3];
  const float* w_right  = (const float*)d_in[4];
  const float* b_right  = (const float*)d_in[5];
  const float* bn_r_w   = (const float*)d_in[6];
  const float* bn_r_b   = (const float*)d_in[7];
  const float* w_l1     = (const float*)d_in[8];
  const float* b_l1     = (const float*)d_in[9];
  const float* bn1_w    = (const float*)d_in[10];
  const float* bn1_b    = (const float*)d_in[11];
  const float* w_l2     = (const float*)d_in[12];
  const float* b_l2     = (const float*)d_in[13];
  const float* bn2_w    = (const float*)d_in[14];
  const float* bn2_b    = (const float*)d_in[15];
  float* out = (float*)d_out;

  float* A     = (float*)d_ws;          // 18,432,000 floats
  float* Bb    = A + TOT;               // 18,432,000 floats
  float* Pg    = Bb + TOT;              // 115,200 floats
  float* stGN  = Pg + 115200;           // 24
  float* stBNr = stGN + 24;             // 192
  float* stIN1 = stBNr + 192;           // 384
  float* stIN2 = stIN1 + 384;           // 384

  hipMemsetAsync(stGN, 0, 984 * sizeof(float), stream);

  // feat = conv1x1(x, w_linear)  -> A
  conv_k<<<2000, 256, 0, stream>>>(x, w_linear, nullptr, A);
  // block means + sinkhorn + top-3 cut -> P
  attnA_k<<<1152, 256, 0, stream>>>(A, Pg);
  // attention -> Bb (stored directly in feat_attn [B,C,N,W] layout)
  attnB_k<<<11520, 256, 0, stream>>>(A, Pg, Bb);
  // t = swapaxes(feat_attn,1,3) + x -> A
  trans_add_k<<<2000, 256, 0, stream>>>(Bb, x, A);
  // groupnorm stats + apply (y in A)
  gnstats_k<<<384, 256, 0, stream>>>(A, stGN);
  gn2_k<<<2048, 256, 0, stream>>>(A, stGN, gn_w, gn_b);
  // right = conv(y, w_right)+b -> d_out (raw); BN stats
  conv_k<<<2000, 256, 0, stream>>>(A, w_right, b_right, out);
  chstats_k<1><<<192, 256, 0, stream>>>(out, stBNr);
  // l1 = conv(y, w_l1)+b -> Bb (raw); IN stats; left1 = relu(BN1(IN(l1))) in place
  conv_k<<<2000, 256, 0, stream>>>(A, w_l1, b_l1, Bb);
  chstats_k<0><<<192, 256, 0, stream>>>(Bb, stIN1);
  bnin_relu_k<<<2048, 256, 0, stream>>>(Bb, stIN1, bn1_w, bn1_b);
  // l2 = conv(left1, w_l2)+b -> A (raw); IN stats
  conv_k<<<2000, 256, 0, stream>>>(Bb, w_l2, b_l2, A);
  chstats_k<0><<<192, 256, 0, stream>>>(A, stIN2);
  // out = relu(BN2(IN(l2)) + BNr(right_raw))
  final_k<<<2048, 256, 0, stream>>>(out, A, stBNr, stIN2,
                                    bn_r_w, bn_r_b, bn2_w, bn2_b);
}

// Round 5
// 784.489 us; speedup vs baseline: 1.1753x; 1.1729x over previous
//
#include <hip/hip_runtime.h>
#include <math.h>

#define CNW 9216000      // C*N*W = 96*1000*96
#define TOT 18432000     // B*C*N*W
#define EPSV 1e-5f
#define ITEMP 0.10206207261596575f   // 1/sqrt(96)

// ---------------- conv1x1: out[b,o,n,w] = sum_c W[o,c]*x[b,c,n,w] (+bias) ----
// one block per (b,n); LDS tiles padded to 100 floats/row (16B-aligned rows)
__global__ __launch_bounds__(256) void conv_k(const float* __restrict__ x,
    const float* __restrict__ w, const float* __restrict__ bias,
    float* __restrict__ out) {
  __shared__ float xt[96 * 100];
  __shared__ float wt[96 * 100];
  int b = blockIdx.x / 1000, n = blockIdx.x % 1000;
  int t = threadIdx.x;
  const float* xp = x + b * CNW + n * 96;
  for (int i = t; i < 9216; i += 256) {
    int cc = i / 96, j = i % 96;
    xt[cc * 100 + j] = xp[cc * 96000 + j];
    wt[cc * 100 + j] = w[i];            // wt[o][c] since i = o*96+c
  }
  __syncthreads();
  if (t < 192) {
    int wq = t % 24, og = t / 24;       // w = 4*wq+r, o = og*12+oo
    float4 acc[12];
#pragma unroll
    for (int oo = 0; oo < 12; ++oo) acc[oo] = make_float4(0.f, 0.f, 0.f, 0.f);
    for (int cq = 0; cq < 24; ++cq) {
      float4 xv0 = *(const float4*)&xt[(4 * cq + 0) * 100 + 4 * wq];
      float4 xv1 = *(const float4*)&xt[(4 * cq + 1) * 100 + 4 * wq];
      float4 xv2 = *(const float4*)&xt[(4 * cq + 2) * 100 + 4 * wq];
      float4 xv3 = *(const float4*)&xt[(4 * cq + 3) * 100 + 4 * wq];
#pragma unroll
      for (int oo = 0; oo < 12; ++oo) {
        int o = og * 12 + oo;
        float4 wv = *(const float4*)&wt[o * 100 + 4 * cq];
        acc[oo].x += wv.x * xv0.x + wv.y * xv1.x + wv.z * xv2.x + wv.w * xv3.x;
        acc[oo].y += wv.x * xv0.y + wv.y * xv1.y + wv.z * xv2.y + wv.w * xv3.y;
        acc[oo].z += wv.x * xv0.z + wv.y * xv1.z + wv.z * xv2.z + wv.w * xv3.z;
        acc[oo].w += wv.x * xv0.w + wv.y * xv1.w + wv.z * xv2.w + wv.w * xv3.w;
      }
    }
    float* op = out + b * CNW + n * 96 + 4 * wq;
#pragma unroll
    for (int oo = 0; oo < 12; ++oo) {
      int o = og * 12 + oo;
      float4 v = acc[oo];
      if (bias) { float bb = bias[o]; v.x += bb; v.y += bb; v.z += bb; v.w += bb; }
      *(float4*)&op[o * 96000] = v;
    }
  }
}

// ---------------- attention kernel A: block means -> sinkhorn -> top3 cut -> P
__global__ __launch_bounds__(256) void attnA_k(const float* __restrict__ feat,
                                               float* __restrict__ Pg) {
  int head = blockIdx.x;
  int b = head / 576, rem = head % 576, c = rem / 6, gr = rem % 6;
  const float* fb = feat + b * CNW + c * 96000 + gr * 16;
  __shared__ float qm[160];     // [10][16]
  __shared__ float L[110];      // [10][11]
  int t = threadIdx.x;
  if (t < 160) {
    int m = t / 16, j = t % 16;
    float s = 0.f;
    for (int ss = 0; ss < 100; ++ss) s += fb[(m * 100 + ss) * 96 + j];
    qm[m * 16 + j] = s * 0.01f;
  }
  __syncthreads();
  if (t < 100) {
    int m = t / 10, n2 = t % 10;
    float acc = 0.f;
#pragma unroll
    for (int j = 0; j < 16; ++j) acc += qm[m * 16 + j] * qm[n2 * 16 + j];
    L[m * 11 + n2] = acc * ITEMP;
  }
  __syncthreads();
  for (int it = 0; it < 8; ++it) {
    if (t < 10) {   // row LSE (axis=-1)
      float mx = -3.4e38f;
      for (int n2 = 0; n2 < 10; ++n2) mx = fmaxf(mx, L[t * 11 + n2]);
      float s = 0.f;
      for (int n2 = 0; n2 < 10; ++n2) s += expf(L[t * 11 + n2] - mx);
      float lse = mx + logf(s);
      for (int n2 = 0; n2 < 10; ++n2) L[t * 11 + n2] -= lse;
    }
    __syncthreads();
    if (t < 10) {   // col LSE (axis=-2)
      float mx = -3.4e38f;
      for (int m = 0; m < 10; ++m) mx = fmaxf(mx, L[m * 11 + t]);
      float s = 0.f;
      for (int m = 0; m < 10; ++m) s += expf(L[m * 11 + t] - mx);
      float lse = mx + logf(s);
      for (int m = 0; m < 10; ++m) L[m * 11 + t] -= lse;
    }
    __syncthreads();
  }
  if (t < 10) {
    float p[10];
#pragma unroll
    for (int n2 = 0; n2 < 10; ++n2) p[n2] = expf(L[t * 11 + n2]);
    int i1 = -1, i2 = -1;
    float m1 = -1.f, m2 = -1.f, m3 = -1.f;
#pragma unroll
    for (int n2 = 0; n2 < 10; ++n2) if (p[n2] > m1) { m1 = p[n2]; i1 = n2; }
#pragma unroll
    for (int n2 = 0; n2 < 10; ++n2) if (n2 != i1 && p[n2] > m2) { m2 = p[n2]; i2 = n2; }
#pragma unroll
    for (int n2 = 0; n2 < 10; ++n2) if (n2 != i1 && n2 != i2 && p[n2] > m3) m3 = p[n2];
#pragma unroll
    for (int n2 = 0; n2 < 10; ++n2)
      Pg[head * 100 + t * 10 + n2] = (p[n2] >= m3) ? p[n2] : 0.f;
  }
}

// ---------------- attention kernel B (flash-style, register rows) -----------
// Block = one (head, m-block), 128 threads. Phase 1: build mixed sk/sv in LDS
// (16 KB). Phase 2: thread s owns q-row s; loops 100 mixed keys with online
// softmax (defer-rescale thr=8), accumulating 16-wide output in registers.
// All sk/sv reads in the loop are same-address broadcasts (conflict-free).
__global__ __launch_bounds__(128) void attnB_k(const float* __restrict__ feat,
    const float* __restrict__ Pg, float* __restrict__ out) {
  int m = blockIdx.x % 10;
  int head = blockIdx.x / 10;
  int b = head / 576, rem = head % 576, c = rem / 6, gr = rem % 6;
  const float* fb = feat + b * CNW + c * 96000 + gr * 16;
  __shared__ float sk[100 * 20];
  __shared__ float sv[100 * 20];
  int t = threadIdx.x;
  float p[10];
#pragma unroll
  for (int n2 = 0; n2 < 10; ++n2) p[n2] = Pg[head * 100 + m * 10 + n2];
  // build mixed sk/sv (v = elu(k), branchless via __expf)
  for (int i4 = t; i4 < 400; i4 += 128) {
    int s = i4 >> 2, q = i4 & 3;
    float4 ak = make_float4(0.f, 0.f, 0.f, 0.f);
    float4 av = make_float4(0.f, 0.f, 0.f, 0.f);
#pragma unroll
    for (int n2 = 0; n2 < 10; ++n2) {
      if (p[n2] != 0.f) {
        float4 kv = *(const float4*)&fb[(n2 * 100 + s) * 96 + 4 * q];
        float pe = p[n2];
        ak.x += pe * kv.x; ak.y += pe * kv.y; ak.z += pe * kv.z; ak.w += pe * kv.w;
        // elu(x) = max(x,0) + exp(min(x,0)) - 1   (branchless)
        float ex = fmaxf(kv.x, 0.f) + __expf(fminf(kv.x, 0.f)) - 1.f;
        float ey = fmaxf(kv.y, 0.f) + __expf(fminf(kv.y, 0.f)) - 1.f;
        float ez = fmaxf(kv.z, 0.f) + __expf(fminf(kv.z, 0.f)) - 1.f;
        float ew = fmaxf(kv.w, 0.f) + __expf(fminf(kv.w, 0.f)) - 1.f;
        av.x += pe * ex; av.y += pe * ey; av.z += pe * ez; av.w += pe * ew;
      }
    }
    *(float4*)&sk[s * 20 + 4 * q] = ak;
    *(float4*)&sv[s * 20 + 4 * q] = av;
  }
  __syncthreads();
  if (t < 100) {
    const float* qp = &fb[(m * 100 + t) * 96];
    float4 q0 = *(const float4*)&qp[0];
    float4 q1 = *(const float4*)&qp[4];
    float4 q2 = *(const float4*)&qp[8];
    float4 q3 = *(const float4*)&qp[12];
    float4 o0 = make_float4(0.f, 0.f, 0.f, 0.f);
    float4 o1 = o0, o2 = o0, o3 = o0;
    float mmax = -3.4e38f, lsum = 0.f;
    for (int tt = 0; tt < 100; ++tt) {
      float4 k0 = *(const float4*)&sk[tt * 20 + 0];
      float4 k1 = *(const float4*)&sk[tt * 20 + 4];
      float4 k2 = *(const float4*)&sk[tt * 20 + 8];
      float4 k3 = *(const float4*)&sk[tt * 20 + 12];
      float d0 = q0.x * k0.x + q0.y * k0.y + q0.z * k0.z + q0.w * k0.w;
      float d1 = q1.x * k1.x + q1.y * k1.y + q1.z * k1.z + q1.w * k1.w;
      float d2 = q2.x * k2.x + q2.y * k2.y + q2.z * k2.z + q2.w * k2.w;
      float d3 = q3.x * k3.x + q3.y * k3.y + q3.z * k3.z + q3.w * k3.w;
      float sc = (d0 + d1 + d2 + d3) * ITEMP;
      float d = sc - mmax;
      if (d > 8.f) {          // defer-rescale: taken ~only on first iteration
        float scal = __expf(-d);   // d may be huge (mmax=-inf): exp(-inf)=0 ok
        lsum *= scal;
        o0.x *= scal; o0.y *= scal; o0.z *= scal; o0.w *= scal;
        o1.x *= scal; o1.y *= scal; o1.z *= scal; o1.w *= scal;
        o2.x *= scal; o2.y *= scal; o2.z *= scal; o2.w *= scal;
        o3.x *= scal; o3.y *= scal; o3.z *= scal; o3.w *= scal;
        mmax = sc; d = 0.f;
      }
      float e = __expf(d);
      lsum += e;
      float4 v0 = *(const float4*)&sv[tt * 20 + 0];
      float4 v1 = *(const float4*)&sv[tt * 20 + 4];
      float4 v2 = *(const float4*)&sv[tt * 20 + 8];
      float4 v3 = *(const float4*)&sv[tt * 20 + 12];
      o0.x += e * v0.x; o0.y += e * v0.y; o0.z += e * v0.z; o0.w += e * v0.w;
      o1.x += e * v1.x; o1.y += e * v1.y; o1.z += e * v1.z; o1.w += e * v1.w;
      o2.x += e * v2.x; o2.y += e * v2.y; o2.z += e * v2.z; o2.w += e * v2.w;
      o3.x += e * v3.x; o3.y += e * v3.y; o3.z += e * v3.z; o3.w += e * v3.w;
    }
    float ri = 1.f / lsum;
    float* ob = out + b * CNW + c * 96000 + gr * 16 + (m * 100 + t) * 96;
    float4 w0 = make_float4(o0.x * ri, o0.y * ri, o0.z * ri, o0.w * ri);
    float4 w1 = make_float4(o1.x * ri, o1.y * ri, o1.z * ri, o1.w * ri);
    float4 w2 = make_float4(o2.x * ri, o2.y * ri, o2.z * ri, o2.w * ri);
    float4 w3 = make_float4(o3.x * ri, o3.y * ri, o3.z * ri, o3.w * ri);
    *(float4*)&ob[0]  = w0;
    *(float4*)&ob[4]  = w1;
    *(float4*)&ob[8]  = w2;
    *(float4*)&ob[12] = w3;
  }
}

// ---------------- t = swapaxes(feat_attn,1,3) + x  (per (b,n) 96x96 tile) ----
__global__ __launch_bounds__(256) void trans_add_k(const float* __restrict__ z,
    const float* __restrict__ x, float* __restrict__ out) {
  __shared__ float ld[96 * 97];
  int b = blockIdx.x / 1000, n = blockIdx.x % 1000;
  int t = threadIdx.x;
  const float* zp = z + b * CNW + n * 96;
  for (int i = t; i < 9216; i += 256) {
    int r = i / 96, col = i % 96;
    ld[r * 97 + col] = zp[r * 96000 + col];
  }
  __syncthreads();
  const float* xp = x + b * CNW + n * 96;
  float* op = out + b * CNW + n * 96;
  for (int i = t; i < 9216; i += 256) {
    int cc = i / 96, ww = i % 96;
    op[cc * 96000 + ww] = ld[ww * 97 + cc] + xp[cc * 96000 + ww];
  }
}

// ---------------- GN stats: 12 contiguous (b,group) slices of 1.536M floats --
__global__ __launch_bounds__(256) void gnstats_k(const float* __restrict__ a,
                                                 float* __restrict__ st) {
  int slice = blockIdx.x >> 5, chunk = blockIdx.x & 31;
  const float4* p = (const float4*)(a + slice * 1536000 + chunk * 48000);
  float s = 0.f, q = 0.f;
  for (int i = threadIdx.x; i < 12000; i += 256) {
    float4 v = p[i];
    s += v.x + v.y + v.z + v.w;
    q += v.x * v.x + v.y * v.y + v.z * v.z + v.w * v.w;
  }
#pragma unroll
  for (int d = 32; d >= 1; d >>= 1) { s += __shfl_down(s, d, 64); q += __shfl_down(q, d, 64); }
  __shared__ float ls[4], lq[4];
  int wid = threadIdx.x >> 6;
  if ((threadIdx.x & 63) == 0) { ls[wid] = s; lq[wid] = q; }
  __syncthreads();
  if (threadIdx.x == 0) {
    atomicAdd(&st[slice * 2 + 0], ls[0] + ls[1] + ls[2] + ls[3]);
    atomicAdd(&st[slice * 2 + 1], lq[0] + lq[1] + lq[2] + lq[3]);
  }
}

// ---------------- per-channel / per-(b,channel) stats over one channel slice -
template <int PER_CH>
__global__ __launch_bounds__(256) void chstats_k(const float* __restrict__ src,
                                                 float* __restrict__ st) {
  int b = blockIdx.x / 96, o = blockIdx.x % 96;
  const float4* p = (const float4*)(src + b * CNW + o * 96000);
  float s = 0.f, q = 0.f;
  for (int i = threadIdx.x; i < 24000; i += 256) {
    float4 v = p[i];
    s += v.x + v.y + v.z + v.w;
    q += v.x * v.x + v.y * v.y + v.z * v.z + v.w * v.w;
  }
#pragma unroll
  for (int d = 32; d >= 1; d >>= 1) { s += __shfl_down(s, d, 64); q += __shfl_down(q, d, 64); }
  __shared__ float ls[4], lq[4];
  int wid = threadIdx.x >> 6;
  if ((threadIdx.x & 63) == 0) { ls[wid] = s; lq[wid] = q; }
  __syncthreads();
  if (threadIdx.x == 0) {
    float S = ls[0] + ls[1] + ls[2] + ls[3];
    float Q = lq[0] + lq[1] + lq[2] + lq[3];
    if (PER_CH) { atomicAdd(&st[o * 2 + 0], S); atomicAdd(&st[o * 2 + 1], Q); }
    else { st[(b * 96 + o) * 2 + 0] = S; st[(b * 96 + o) * 2 + 1] = Q; }
  }
}

// ---------------- GroupNorm apply (in place) --------------------------------
__global__ __launch_bounds__(256) void gn2_k(float* __restrict__ a,
    const float* __restrict__ st, const float* __restrict__ gw,
    const float* __restrict__ gb) {
  int stride = gridDim.x * 256;
  for (int i4 = blockIdx.x * 256 + threadIdx.x; i4 < 4608000; i4 += stride) {
    int i = i4 * 4;
    int b = i / CNW, c = (i / 96000) % 96, g = c >> 4;
    float m = st[(b * 6 + g) * 2 + 0] * (1.f / 1536000.f);
    float v = st[(b * 6 + g) * 2 + 1] * (1.f / 1536000.f) - m * m;
    float scv = rsqrtf(v + EPSV) * gw[c];
    float sh = gb[c] - m * scv;
    float4 x = ((float4*)a)[i4];
    x.x = x.x * scv + sh; x.y = x.y * scv + sh; x.z = x.z * scv + sh; x.w = x.w * scv + sh;
    ((float4*)a)[i4] = x;
  }
}

// ---------------- left1 = relu(BN1(IN(l1))) in place -------------------------
// BN-after-IN analytics: mean = 0 exactly; var[c] = avg_b v_bc/(v_bc+eps)
__global__ __launch_bounds__(256) void bnin_relu_k(float* __restrict__ tbuf,
    const float* __restrict__ st, const float* __restrict__ bw,
    const float* __restrict__ bb) {
  int stride = gridDim.x * 256;
  for (int i4 = blockIdx.x * 256 + threadIdx.x; i4 < 4608000; i4 += stride) {
    int i = i4 * 4;
    int b = i / CNW, o = (i / 96000) % 96;
    const float inv = 1.f / 96000.f;
    float m0 = st[o * 2] * inv,        v0 = st[o * 2 + 1] * inv - m0 * m0;
    float m1 = st[(96 + o) * 2] * inv, v1 = st[(96 + o) * 2 + 1] * inv - m1 * m1;
    float bv = 0.5f * (v0 / (v0 + EPSV) + v1 / (v1 + EPSV));
    float bscale = rsqrtf(bv + EPSV) * bw[o];
    float mi = b ? m1 : m0, vi = b ? v1 : v0;
    float scv = rsqrtf(vi + EPSV) * bscale;
    float sh = bb[o] - mi * scv;
    float4 x = ((float4*)tbuf)[i4];
    x.x = fmaxf(x.x * scv + sh, 0.f); x.y = fmaxf(x.y * scv + sh, 0.f);
    x.z = fmaxf(x.z * scv + sh, 0.f); x.w = fmaxf(x.w * scv + sh, 0.f);
    ((float4*)tbuf)[i4] = x;
  }
}

// ---------------- out = relu( BN2(IN(l2)) + BNr(t1) ), in place over d_out ---
__global__ __launch_bounds__(256) void final_k(float* __restrict__ outp,
    const float* __restrict__ l2, const float* __restrict__ stR,
    const float* __restrict__ st2, const float* __restrict__ rw,
    const float* __restrict__ rb, const float* __restrict__ w2,
    const float* __restrict__ b2) {
  int stride = gridDim.x * 256;
  for (int i4 = blockIdx.x * 256 + threadIdx.x; i4 < 4608000; i4 += stride) {
    int i = i4 * 4;
    int b = i / CNW, o = (i / 96000) % 96;
    // right path: plain BN of raw conv output held in outp
    float mr = stR[o * 2] * (1.f / 192000.f);
    float vr = stR[o * 2 + 1] * (1.f / 192000.f) - mr * mr;
    float rs = rsqrtf(vr + EPSV) * rw[o];
    float rsh = rb[o] - mr * rs;
    // left path: IN then analytic BN
    const float inv = 1.f / 96000.f;
    float m0 = st2[o * 2] * inv,        v0 = st2[o * 2 + 1] * inv - m0 * m0;
    float m1 = st2[(96 + o) * 2] * inv, v1 = st2[(96 + o) * 2 + 1] * inv - m1 * m1;
    float bv = 0.5f * (v0 / (v0 + EPSV) + v1 / (v1 + EPSV));
    float ls = rsqrtf(bv + EPSV) * w2[o];
    float mi = b ? m1 : m0, vi = b ? v1 : v0;
    float lsc = rsqrtf(vi + EPSV) * ls;
    float lsh = b2[o] - mi * lsc;
    float4 R = ((float4*)outp)[i4];
    float4 L = ((const float4*)l2)[i4];
    float4 O;
    O.x = fmaxf(R.x * rs + rsh + L.x * lsc + lsh, 0.f);
    O.y = fmaxf(R.y * rs + rsh + L.y * lsc + lsh, 0.f);
    O.z = fmaxf(R.z * rs + rsh + L.z * lsc + lsh, 0.f);
    O.w = fmaxf(R.w * rs + rsh + L.w * lsc + lsh, 0.f);
    ((float4*)outp)[i4] = O;
  }
}

extern "C" void kernel_launch(void* const* d_in, const int* in_sizes, int n_in,
                              void* d_out, int out_size, void* d_ws, size_t ws_size,
                              hipStream_t stream) {
  const float* x        = (const float*)d_in[0];
  const float* w_linear = (const float*)d_in[1];
  const float* gn_w     = (const float*)d_in[2];
  const float* gn_b     = (const float*)d_in[3];
  const float* w_right  = (const float*)d_in[4];
  const float* b_right  = (const float*)d_in[5];
  const float* bn_r_w   = (const float*)d_in[6];
  const float* bn_r_b   = (const float*)d_in[7];
  const float* w_l1     = (const float*)d_in[8];
  const float* b_l1     = (const float*)d_in[9];
  const float* bn1_w    = (const float*)d_in[10];
  const float* bn1_b    = (const float*)d_in[11];
  const float* w_l2     = (const float*)d_in[12];
  const float* b_l2     = (const float*)d_in[13];
  const float* bn2_w    = (const float*)d_in[14];
  const float* bn2_b    = (const float*)d_in[15];
  float* out = (float*)d_out;

  float* A     = (float*)d_ws;          // 18,432,000 floats
  float* Bb    = A + TOT;               // 18,432,000 floats
  float* Pg    = Bb + TOT;              // 115,200 floats
  float* stGN  = Pg + 115200;           // 24
  float* stBNr = stGN + 24;             // 192
  float* stIN1 = stBNr + 192;           // 384
  float* stIN2 = stIN1 + 384;           // 384

  hipMemsetAsync(stGN, 0, 984 * sizeof(float), stream);

  // feat = conv1x1(x, w_linear)  -> A
  conv_k<<<2000, 256, 0, stream>>>(x, w_linear, nullptr, A);
  // block means + sinkhorn + top-3 cut -> P
  attnA_k<<<1152, 256, 0, stream>>>(A, Pg);
  // attention -> Bb (stored directly in feat_attn [B,C,N,W] layout)
  attnB_k<<<11520, 128, 0, stream>>>(A, Pg, Bb);
  // t = swapaxes(feat_attn,1,3) + x -> A
  trans_add_k<<<2000, 256, 0, stream>>>(Bb, x, A);
  // groupnorm stats + apply (y in A)
  gnstats_k<<<384, 256, 0, stream>>>(A, stGN);
  gn2_k<<<2048, 256, 0, stream>>>(A, stGN, gn_w, gn_b);
  // right = conv(y, w_right)+b -> d_out (raw); BN stats
  conv_k<<<2000, 256, 0, stream>>>(A, w_right, b_right, out);
  chstats_k<1><<<192, 256, 0, stream>>>(out, stBNr);
  // l1 = conv(y, w_l1)+b -> Bb (raw); IN stats; left1 = relu(BN1(IN(l1))) in place
  conv_k<<<2000, 256, 0, stream>>>(A, w_l1, b_l1, Bb);
  chstats_k<0><<<192, 256, 0, stream>>>(Bb, stIN1);
  bnin_relu_k<<<2048, 256, 0, stream>>>(Bb, stIN1, bn1_w, bn1_b);
  // l2 = conv(left1, w_l2)+b -> A (raw); IN stats
  conv_k<<<2000, 256, 0, stream>>>(Bb, w_l2, b_l2, A);
  chstats_k<0><<<192, 256, 0, stream>>>(A, stIN2);
  // out = relu(BN2(IN(l2)) + BNr(right_raw))
  final_k<<<2048, 256, 0, stream>>>(out, A, stBNr, stIN2,
                                    bn_r_w, bn_r_b, bn2_w, bn2_b);
}